// Round 10
// baseline (425.270 us; speedup 1.0000x reference)
//
#include <hip/hip_runtime.h>

#define BB 4
#define LL 4096
#define DD 512

typedef __attribute__((ext_vector_type(8))) short bf16x8;
typedef __attribute__((ext_vector_type(4))) float f32x4;
typedef __attribute__((ext_vector_type(4))) unsigned short ushort4v;
typedef __attribute__((ext_vector_type(4))) unsigned int u32x4;

__device__ __forceinline__ unsigned short bf16_rne(float x) {
    unsigned u = __float_as_uint(x);
    unsigned r = (u + 0x7FFFu + ((u >> 16) & 1u)) >> 16;
    return (unsigned short)r;
}

// ---------------------------------------------------------------------------
// prep: fused {split_x | gemm_tn_M} — independent work, one launch.
//   blocks [0, 8192):  X fp32 -> (Xh, Xl) bf16 hi/lo pair (4 elems/thread)
//   blocks [8192, 8256): Mt[i,j] = scale * sum_d Wk[d,i] * Wq[d,j]  (64x64)
// ---------------------------------------------------------------------------
__global__ __launch_bounds__(256) void prep(
    const float* __restrict__ X,
    unsigned short* __restrict__ Xh, unsigned short* __restrict__ Xl,
    const float* __restrict__ A,  // Wk
    const float* __restrict__ B,  // Wq
    unsigned short* __restrict__ Mh, unsigned short* __restrict__ Ml,
    float scale) {
    __shared__ float As[16][68];
    __shared__ float Bs[16][68];

    if (blockIdx.x < 8192) {
        const size_t i = ((size_t)blockIdx.x * 256 + threadIdx.x) * 4;
        float4 x4 = *reinterpret_cast<const float4*>(X + i);
        float v[4] = {x4.x, x4.y, x4.z, x4.w};
        ushort4v h4, l4;
        #pragma unroll
        for (int j = 0; j < 4; ++j) {
            unsigned short h = bf16_rne(v[j]);
            float lo = v[j] - __uint_as_float((unsigned)h << 16);
            h4[j] = h;
            l4[j] = bf16_rne(lo);
        }
        *reinterpret_cast<ushort4v*>(Xh + i) = h4;
        *reinterpret_cast<ushort4v*>(Xl + i) = l4;
        return;
    }

    const int bid = blockIdx.x - 8192;
    const int tid = threadIdx.x;
    const int tx = tid & 15, ty = tid >> 4;
    const int iBase = (bid >> 3) * 64;
    const int jBase = (bid & 7) * 64;
    const int dr = tid >> 4;
    const int c4 = (tid & 15) << 2;

    float acc[4][4] = {};
    for (int d0 = 0; d0 < DD; d0 += 16) {
        float4 a4 = *reinterpret_cast<const float4*>(A + (size_t)(d0 + dr) * DD + iBase + c4);
        float4 b4 = *reinterpret_cast<const float4*>(B + (size_t)(d0 + dr) * DD + jBase + c4);
        __syncthreads();
        *reinterpret_cast<float4*>(&As[dr][c4]) = a4;
        *reinterpret_cast<float4*>(&Bs[dr][c4]) = b4;
        __syncthreads();
        #pragma unroll
        for (int t = 0; t < 16; ++t) {
            float4 q4 = *reinterpret_cast<const float4*>(&As[t][ty << 2]);
            float4 k4 = *reinterpret_cast<const float4*>(&Bs[t][tx << 2]);
            float q[4] = {q4.x, q4.y, q4.z, q4.w};
            float k[4] = {k4.x, k4.y, k4.z, k4.w};
            #pragma unroll
            for (int i = 0; i < 4; ++i)
                #pragma unroll
                for (int j = 0; j < 4; ++j)
                    acc[i][j] = fmaf(q[i], k[j], acc[i][j]);
        }
    }
    #pragma unroll
    for (int i = 0; i < 4; ++i)
        #pragma unroll
        for (int j = 0; j < 4; ++j) {
            float v = acc[i][j] * scale;
            unsigned short h = bf16_rne(v);
            float lo = v - __uint_as_float((unsigned)h << 16);
            size_t off = (size_t)(iBase + (ty << 2) + i) * DD + jBase + (tx << 2) + j;
            Mh[off] = h;
            Ml[off] = bf16_rne(lo);
        }
}

// ---------------------------------------------------------------------------
// Staging helpers (round-2/3 validated).
// ---------------------------------------------------------------------------
#define GLOAD_LDS16(SRC, DST)                                                  \
    __builtin_amdgcn_global_load_lds(                                          \
        (const __attribute__((address_space(1))) void*)(SRC),                  \
        (__attribute__((address_space(3))) void*)(DST), 16, 0, 0)

// stage 8 rows x 64 bf16 cols (1 KB), linear LDS dest, source column chunk
// pre-swizzled c^r (row0 must be a multiple of 8).
__device__ __forceinline__ void stage8(const unsigned short* __restrict__ g,
                                       unsigned short* l) {
    const int ln = threadIdx.x & 63;
    const int r = ln >> 3;
    const int c = ln & 7;
    const unsigned short* src = g + (size_t)r * DD + ((c ^ r) << 3);
    GLOAD_LDS16(src, l);
}

// read one 16x32 fragment with the read-side XOR swizzle.
__device__ __forceinline__ bf16x8 ldfrag(const unsigned short* base, int row16,
                                         int kk) {
    const int lane = threadIdx.x & 63;
    const int r = row16 + (lane & 15);
    const int boff = r * 128 + ((((kk + ((lane >> 4) << 3)) << 1)) ^ ((r & 7) << 4));
    return *reinterpret_cast<const bf16x8*>(
        reinterpret_cast<const char*>(base) + boff);
}

// ---------------------------------------------------------------------------
// T = Xsplit @ Mtsplit^T ("NT"). 3-product input accuracy, stores only Th.
// XCD swizzle + coalesced LDS-repack epilogue (round-6 validated).
// ---------------------------------------------------------------------------
__global__ __launch_bounds__(256, 3) void gemm_nt_T(
    const unsigned short* __restrict__ Xh_g, const unsigned short* __restrict__ Xl_g,
    const unsigned short* __restrict__ Mh_g, const unsigned short* __restrict__ Ml_g,
    unsigned short* __restrict__ Th_g) {
    __shared__ unsigned short Ah_s[128][64];
    __shared__ unsigned short Al_s[128][64];
    __shared__ unsigned short Bh_s[64][64];
    __shared__ unsigned short Bl_s[64][64];

    // bijective swizzle: 1024 blocks, XCD gets 16 row-tiles x all 8 col-tiles
    const int lin = blockIdx.x;
    const int wgid = ((lin & 7) << 7) + (lin >> 3);
    const int rBase = (wgid >> 3) * 128;
    const int cBase = (wgid & 7) * 64;

    const int w = threadIdx.x >> 6;
    const int lane = threadIdx.x & 63;
    const int wq = (w >> 1) * 64;
    const int wk = (w & 1) * 32;

    f32x4 acc[4][2] = {};

    for (int dcc = 0; dcc < 8; ++dcc) {
        const int dc = dcc << 6;
        __syncthreads();
        #pragma unroll
        for (int s = 0; s < 4; ++s) {
            const int r0 = w * 32 + s * 8;
            stage8(Xh_g + (size_t)(rBase + r0) * DD + dc, &Ah_s[r0][0]);
            stage8(Xl_g + (size_t)(rBase + r0) * DD + dc, &Al_s[r0][0]);
        }
        #pragma unroll
        for (int s = 0; s < 2; ++s) {
            const int r0 = w * 16 + s * 8;
            stage8(Mh_g + (size_t)(cBase + r0) * DD + dc, &Bh_s[r0][0]);
            stage8(Ml_g + (size_t)(cBase + r0) * DD + dc, &Bl_s[r0][0]);
        }
        __syncthreads();
        #pragma unroll
        for (int kk = 0; kk < 64; kk += 32) {
            bf16x8 bh0 = ldfrag(&Bh_s[0][0], wk + 0, kk);
            bf16x8 bh1 = ldfrag(&Bh_s[0][0], wk + 16, kk);
            bf16x8 bl0 = ldfrag(&Bl_s[0][0], wk + 0, kk);
            bf16x8 bl1 = ldfrag(&Bl_s[0][0], wk + 16, kk);
            #pragma unroll
            for (int i = 0; i < 4; ++i) {
                bf16x8 ah = ldfrag(&Ah_s[0][0], wq + i * 16, kk);
                bf16x8 al = ldfrag(&Al_s[0][0], wq + i * 16, kk);
                acc[i][0] = __builtin_amdgcn_mfma_f32_16x16x32_bf16(ah, bh0, acc[i][0], 0, 0, 0);
                acc[i][0] = __builtin_amdgcn_mfma_f32_16x16x32_bf16(ah, bl0, acc[i][0], 0, 0, 0);
                acc[i][0] = __builtin_amdgcn_mfma_f32_16x16x32_bf16(al, bh0, acc[i][0], 0, 0, 0);
                acc[i][1] = __builtin_amdgcn_mfma_f32_16x16x32_bf16(ah, bh1, acc[i][1], 0, 0, 0);
                acc[i][1] = __builtin_amdgcn_mfma_f32_16x16x32_bf16(ah, bl1, acc[i][1], 0, 0, 0);
                acc[i][1] = __builtin_amdgcn_mfma_f32_16x16x32_bf16(al, bh1, acc[i][1], 0, 0, 0);
            }
        }
    }

    // --- epilogue: quantize hi into LDS (swizzled), 16B coalesced stores ---
    __syncthreads();  // all waves done reading A/B tiles
    char* hB = reinterpret_cast<char*>(&Ah_s[0][0]);
    #pragma unroll
    for (int i = 0; i < 4; ++i)
        #pragma unroll
        for (int r = 0; r < 4; ++r) {
            const int row = wq + i * 16 + ((lane >> 4) << 2) + r;
            #pragma unroll
            for (int j = 0; j < 2; ++j) {
                const int col = wk + j * 16 + (lane & 15);
                const int bo = (row << 7) + (((col << 1)) ^ ((row & 7) << 4));
                *reinterpret_cast<unsigned short*>(hB + bo) = bf16_rne(acc[i][j][r]);
            }
        }
    __syncthreads();
    const int tid = threadIdx.x;
    #pragma unroll
    for (int s = 0; s < 4; ++s) {
        const int slot = s * 256 + tid;   // 0..1023 ; 8 slots (16B) per row
        const int row = slot >> 3;
        const int sl = slot & 7;
        const int bo = (row << 7) + (((sl << 4)) ^ ((row & 7) << 4));
        u32x4 hv = *reinterpret_cast<const u32x4*>(hB + bo);
        const size_t go = (size_t)(rBase + row) * DD + cBase + (sl << 3);
        *reinterpret_cast<u32x4*>(Th_g + go) = hv;
    }
}

// ---------------------------------------------------------------------------
// Fused MFMA scores + batch-softmax + masked q-reduction into wsum[b,k].
// Round 10: EXACT round-9 body; the ONLY change is __launch_bounds__
// (256,3) -> (256,5). 2-product kernel uses 32 KB LDS -> 5 blocks/CU fit
// (160 KB exactly). This structure lives on inter-block TLP covering the
// barrier drains; occupancy 3->5 blocks/CU is the matched lever.
// ---------------------------------------------------------------------------
__global__ __launch_bounds__(256, 5) void scores_wsum(
    const unsigned short* __restrict__ Qh_g,
    const unsigned short* __restrict__ Kh_g, const unsigned short* __restrict__ Kl_g,
    const int* __restrict__ lens, float* __restrict__ wsum) {
    __shared__ unsigned short Qh_s[128][64];
    __shared__ unsigned short Kh_s[64][64];
    __shared__ unsigned short Kl_s[64][64];

    const int qBase = blockIdx.x * 128;
    const int kBase = blockIdx.y * 64;
    const int w = threadIdx.x >> 6;
    const int lane = threadIdx.x & 63;
    const int wq = (w >> 1) * 64;   // 0 or 64
    const int wk = (w & 1) * 32;    // 0 or 32

    const int l0 = lens[0], l1 = lens[1], l2 = lens[2], l3 = lens[3];

    f32x4 acc[4][4][2] = {};  // [b][i][j] — static indexing everywhere

    #pragma unroll
    for (int b = 0; b < BB; ++b) {
        const unsigned short* qh = Qh_g + (size_t)(b * LL + qBase) * DD;
        const unsigned short* kh = Kh_g + (size_t)(b * LL + kBase) * DD;
        const unsigned short* kl = Kl_g + (size_t)(b * LL + kBase) * DD;
        for (int dcc = 0; dcc < 8; ++dcc) {
            const int dc = dcc << 6;
            __syncthreads();
            #pragma unroll
            for (int s = 0; s < 4; ++s) {
                const int r0 = w * 32 + s * 8;
                stage8(qh + (size_t)r0 * DD + dc, &Qh_s[r0][0]);
            }
            #pragma unroll
            for (int s = 0; s < 2; ++s) {
                const int r0 = w * 16 + s * 8;
                stage8(kh + (size_t)r0 * DD + dc, &Kh_s[r0][0]);
                stage8(kl + (size_t)r0 * DD + dc, &Kl_s[r0][0]);
            }
            __syncthreads();
            #pragma unroll
            for (int kk = 0; kk < 64; kk += 32) {
                bf16x8 bh0 = ldfrag(&Kh_s[0][0], wk + 0, kk);
                bf16x8 bh1 = ldfrag(&Kh_s[0][0], wk + 16, kk);
                bf16x8 bl0 = ldfrag(&Kl_s[0][0], wk + 0, kk);
                bf16x8 bl1 = ldfrag(&Kl_s[0][0], wk + 16, kk);
                #pragma unroll
                for (int i = 0; i < 4; ++i) {
                    bf16x8 ah = ldfrag(&Qh_s[0][0], wq + i * 16, kk);
                    acc[b][i][0] = __builtin_amdgcn_mfma_f32_16x16x32_bf16(ah, bh0, acc[b][i][0], 0, 0, 0);
                    acc[b][i][0] = __builtin_amdgcn_mfma_f32_16x16x32_bf16(ah, bl0, acc[b][i][0], 0, 0, 0);
                    acc[b][i][1] = __builtin_amdgcn_mfma_f32_16x16x32_bf16(ah, bh1, acc[b][i][1], 0, 0, 0);
                    acc[b][i][1] = __builtin_amdgcn_mfma_f32_16x16x32_bf16(ah, bl1, acc[b][i][1], 0, 0, 0);
                }
            }
        }
    }

    // Epilogue: softmax across b per element, mask q rows, reduce over q.
    float psum[4][2] = {};
    #pragma unroll
    for (int i = 0; i < 4; ++i) {
        #pragma unroll
        for (int r = 0; r < 4; ++r) {
            const int q = qBase + wq + i * 16 + ((lane >> 4) << 2) + r;
            #pragma unroll
            for (int j = 0; j < 2; ++j) {
                float e0 = __expf(acc[0][i][j][r]);
                float e1 = __expf(acc[1][i][j][r]);
                float e2 = __expf(acc[2][i][j][r]);
                float e3 = __expf(acc[3][i][j][r]);
                float inv = 1.0f / (e0 + e1 + e2 + e3);
                psum[0][j] += (q < l0) ? e0 * inv : 0.0f;
                psum[1][j] += (q < l1) ? e1 * inv : 0.0f;
                psum[2][j] += (q < l2) ? e2 * inv : 0.0f;
                psum[3][j] += (q < l3) ? e3 * inv : 0.0f;
            }
        }
    }
    #pragma unroll
    for (int bb = 0; bb < 4; ++bb)
        #pragma unroll
        for (int j = 0; j < 2; ++j) {
            float v = psum[bb][j];
            v += __shfl_xor(v, 16);
            v += __shfl_xor(v, 32);
            if (lane < 16)
                atomicAdd(&wsum[bb * LL + kBase + wk + j * 16 + lane], v);
        }
}

// y[b,e] = sum_k wsum[b,k] * X[b,k,e]
__global__ __launch_bounds__(256) void wsum_x(const float* __restrict__ X,
                                              const float* __restrict__ wsum,
                                              float* __restrict__ y) {
    const int b = blockIdx.y;
    const int e = blockIdx.x * 256 + threadIdx.x;
    const int kc = blockIdx.z * 64;
    const float* Xp = X + ((size_t)b * LL + kc) * DD + e;
    const float* wp = wsum + b * LL + kc;
    float a = 0.0f;
    #pragma unroll 4
    for (int k = 0; k < 64; ++k) a = fmaf(wp[k], Xp[(size_t)k * DD], a);
    atomicAdd(&y[b * DD + e], a);
}

// out[b,d] = sum_e y[b,e] * Wv[d,e]
__global__ __launch_bounds__(256) void y_out(const float* __restrict__ Wv,
                                             const float* __restrict__ y,
                                             float* __restrict__ out) {
    const int b = blockIdx.y;
    const int d = blockIdx.x * 256 + threadIdx.x;
    const float* wv = Wv + (size_t)d * DD;
    const float* yb = y + b * DD;
    float a = 0.0f;
    #pragma unroll 4
    for (int e = 0; e < DD; e += 4) {
        float4 w4 = *reinterpret_cast<const float4*>(wv + e);
        float4 y4 = *reinterpret_cast<const float4*>(yb + e);
        a += w4.x * y4.x + w4.y * y4.y + w4.z * y4.z + w4.w * y4.w;
    }
    out[b * DD + d] = a;
}

extern "C" void kernel_launch(void* const* d_in, const int* in_sizes, int n_in,
                              void* d_out, int out_size, void* d_ws, size_t ws_size,
                              hipStream_t stream) {
    const float* X  = (const float*)d_in[0];
    const float* Wq = (const float*)d_in[1];
    const float* Wk = (const float*)d_in[2];
    const float* Wv = (const float*)d_in[3];
    const int* lens = (const int*)d_in[4];
    float* out = (float*)d_out;

    char* ws = (char*)d_ws;
    unsigned short* Xh  = (unsigned short*)ws;                              // 16 MB
    unsigned short* Xl  = (unsigned short*)(ws + ((size_t)16 << 20));       // 16 MB
    unsigned short* Th  = (unsigned short*)(ws + ((size_t)32 << 20));       // 16 MB
    unsigned short* Mth = (unsigned short*)(ws + ((size_t)64 << 20));       // 512 KB
    unsigned short* Mtl = (unsigned short*)(ws + ((size_t)64 << 20) + (512u << 10));
    float* wsum = (float*)(ws + ((size_t)65 << 20));                        // 64 KB
    float* y    = (float*)(ws + ((size_t)65 << 20) + 65536);                // 8 KB

    hipMemsetAsync(wsum, 0,
                   (size_t)BB * LL * sizeof(float) + (size_t)BB * DD * sizeof(float),
                   stream);

    dim3 blk(256);
    // fused split_x (8192 blocks) + gemm_tn_M (64 blocks); scale 1/16 in Mt
    prep<<<dim3(8256), blk, 0, stream>>>(X, Xh, Xl, Wk, Wq, Mth, Mtl, 0.0625f);
    // T[i,f] = sum_e X[i,e] Mt[f,e]  (stores Th only)
    gemm_nt_T<<<dim3(1024), blk, 0, stream>>>(Xh, Xl, Mth, Mtl, Th);
    // S = Th (Xh+Xl)^T, softmax over b, masked q-reduce
    scores_wsum<<<dim3(32, 64), blk, 0, stream>>>(Th, Xh, Xl, lens, wsum);
    wsum_x<<<dim3(2, 4, 64), blk, 0, stream>>>(X, wsum, y);
    y_out<<<dim3(2, 4), blk, 0, stream>>>(Wv, y, out);
}

// Round 11
// 311.403 us; speedup vs baseline: 1.3657x; 1.3657x over previous
//
#include <hip/hip_runtime.h>

#define BB 4
#define LL 4096
#define DD 512

typedef __attribute__((ext_vector_type(8))) short bf16x8;
typedef __attribute__((ext_vector_type(4))) float f32x4;
typedef __attribute__((ext_vector_type(4))) unsigned short ushort4v;
typedef __attribute__((ext_vector_type(4))) unsigned int u32x4;

__device__ __forceinline__ unsigned short bf16_rne(float x) {
    unsigned u = __float_as_uint(x);
    unsigned r = (u + 0x7FFFu + ((u >> 16) & 1u)) >> 16;
    return (unsigned short)r;
}

// ---------------------------------------------------------------------------
// prep: fused {split_x | gemm_tn_M} — independent work, one launch.
//   blocks [0, 8192):  X fp32 -> (Xh, Xl) bf16 hi/lo pair (4 elems/thread)
//   blocks [8192, 8256): Mt[i,j] = scale * sum_d Wk[d,i] * Wq[d,j]  (64x64)
// ---------------------------------------------------------------------------
__global__ __launch_bounds__(256) void prep(
    const float* __restrict__ X,
    unsigned short* __restrict__ Xh, unsigned short* __restrict__ Xl,
    const float* __restrict__ A,  // Wk
    const float* __restrict__ B,  // Wq
    unsigned short* __restrict__ Mh, unsigned short* __restrict__ Ml,
    float scale) {
    __shared__ float As[16][68];
    __shared__ float Bs[16][68];

    if (blockIdx.x < 8192) {
        const size_t i = ((size_t)blockIdx.x * 256 + threadIdx.x) * 4;
        float4 x4 = *reinterpret_cast<const float4*>(X + i);
        float v[4] = {x4.x, x4.y, x4.z, x4.w};
        ushort4v h4, l4;
        #pragma unroll
        for (int j = 0; j < 4; ++j) {
            unsigned short h = bf16_rne(v[j]);
            float lo = v[j] - __uint_as_float((unsigned)h << 16);
            h4[j] = h;
            l4[j] = bf16_rne(lo);
        }
        *reinterpret_cast<ushort4v*>(Xh + i) = h4;
        *reinterpret_cast<ushort4v*>(Xl + i) = l4;
        return;
    }

    const int bid = blockIdx.x - 8192;
    const int tid = threadIdx.x;
    const int tx = tid & 15, ty = tid >> 4;
    const int iBase = (bid >> 3) * 64;
    const int jBase = (bid & 7) * 64;
    const int dr = tid >> 4;
    const int c4 = (tid & 15) << 2;

    float acc[4][4] = {};
    for (int d0 = 0; d0 < DD; d0 += 16) {
        float4 a4 = *reinterpret_cast<const float4*>(A + (size_t)(d0 + dr) * DD + iBase + c4);
        float4 b4 = *reinterpret_cast<const float4*>(B + (size_t)(d0 + dr) * DD + jBase + c4);
        __syncthreads();
        *reinterpret_cast<float4*>(&As[dr][c4]) = a4;
        *reinterpret_cast<float4*>(&Bs[dr][c4]) = b4;
        __syncthreads();
        #pragma unroll
        for (int t = 0; t < 16; ++t) {
            float4 q4 = *reinterpret_cast<const float4*>(&As[t][ty << 2]);
            float4 k4 = *reinterpret_cast<const float4*>(&Bs[t][tx << 2]);
            float q[4] = {q4.x, q4.y, q4.z, q4.w};
            float k[4] = {k4.x, k4.y, k4.z, k4.w};
            #pragma unroll
            for (int i = 0; i < 4; ++i)
                #pragma unroll
                for (int j = 0; j < 4; ++j)
                    acc[i][j] = fmaf(q[i], k[j], acc[i][j]);
        }
    }
    #pragma unroll
    for (int i = 0; i < 4; ++i)
        #pragma unroll
        for (int j = 0; j < 4; ++j) {
            float v = acc[i][j] * scale;
            unsigned short h = bf16_rne(v);
            float lo = v - __uint_as_float((unsigned)h << 16);
            size_t off = (size_t)(iBase + (ty << 2) + i) * DD + jBase + (tx << 2) + j;
            Mh[off] = h;
            Ml[off] = bf16_rne(lo);
        }
}

// ---------------------------------------------------------------------------
// Staging helpers (round-2/3 validated).
// ---------------------------------------------------------------------------
#define GLOAD_LDS16(SRC, DST)                                                  \
    __builtin_amdgcn_global_load_lds(                                          \
        (const __attribute__((address_space(1))) void*)(SRC),                  \
        (__attribute__((address_space(3))) void*)(DST), 16, 0, 0)

// stage 8 rows x 64 bf16 cols (1 KB), linear LDS dest, source column chunk
// pre-swizzled c^r (row0 must be a multiple of 8).
__device__ __forceinline__ void stage8(const unsigned short* __restrict__ g,
                                       unsigned short* l) {
    const int ln = threadIdx.x & 63;
    const int r = ln >> 3;
    const int c = ln & 7;
    const unsigned short* src = g + (size_t)r * DD + ((c ^ r) << 3);
    GLOAD_LDS16(src, l);
}

// read one 16x32 fragment with the read-side XOR swizzle.
__device__ __forceinline__ bf16x8 ldfrag(const unsigned short* base, int row16,
                                         int kk) {
    const int lane = threadIdx.x & 63;
    const int r = row16 + (lane & 15);
    const int boff = r * 128 + ((((kk + ((lane >> 4) << 3)) << 1)) ^ ((r & 7) << 4));
    return *reinterpret_cast<const bf16x8*>(
        reinterpret_cast<const char*>(base) + boff);
}

// ---------------------------------------------------------------------------
// T = Xsplit @ Mtsplit^T ("NT"). 3-product input accuracy, stores only Th.
// XCD swizzle + coalesced LDS-repack epilogue (round-6 validated).
// ---------------------------------------------------------------------------
__global__ __launch_bounds__(256, 3) void gemm_nt_T(
    const unsigned short* __restrict__ Xh_g, const unsigned short* __restrict__ Xl_g,
    const unsigned short* __restrict__ Mh_g, const unsigned short* __restrict__ Ml_g,
    unsigned short* __restrict__ Th_g) {
    __shared__ unsigned short Ah_s[128][64];
    __shared__ unsigned short Al_s[128][64];
    __shared__ unsigned short Bh_s[64][64];
    __shared__ unsigned short Bl_s[64][64];

    // bijective swizzle: 1024 blocks, XCD gets 16 row-tiles x all 8 col-tiles
    const int lin = blockIdx.x;
    const int wgid = ((lin & 7) << 7) + (lin >> 3);
    const int rBase = (wgid >> 3) * 128;
    const int cBase = (wgid & 7) * 64;

    const int w = threadIdx.x >> 6;
    const int lane = threadIdx.x & 63;
    const int wq = (w >> 1) * 64;
    const int wk = (w & 1) * 32;

    f32x4 acc[4][2] = {};

    for (int dcc = 0; dcc < 8; ++dcc) {
        const int dc = dcc << 6;
        __syncthreads();
        #pragma unroll
        for (int s = 0; s < 4; ++s) {
            const int r0 = w * 32 + s * 8;
            stage8(Xh_g + (size_t)(rBase + r0) * DD + dc, &Ah_s[r0][0]);
            stage8(Xl_g + (size_t)(rBase + r0) * DD + dc, &Al_s[r0][0]);
        }
        #pragma unroll
        for (int s = 0; s < 2; ++s) {
            const int r0 = w * 16 + s * 8;
            stage8(Mh_g + (size_t)(cBase + r0) * DD + dc, &Bh_s[r0][0]);
            stage8(Ml_g + (size_t)(cBase + r0) * DD + dc, &Bl_s[r0][0]);
        }
        __syncthreads();
        #pragma unroll
        for (int kk = 0; kk < 64; kk += 32) {
            bf16x8 bh0 = ldfrag(&Bh_s[0][0], wk + 0, kk);
            bf16x8 bh1 = ldfrag(&Bh_s[0][0], wk + 16, kk);
            bf16x8 bl0 = ldfrag(&Bl_s[0][0], wk + 0, kk);
            bf16x8 bl1 = ldfrag(&Bl_s[0][0], wk + 16, kk);
            #pragma unroll
            for (int i = 0; i < 4; ++i) {
                bf16x8 ah = ldfrag(&Ah_s[0][0], wq + i * 16, kk);
                bf16x8 al = ldfrag(&Al_s[0][0], wq + i * 16, kk);
                acc[i][0] = __builtin_amdgcn_mfma_f32_16x16x32_bf16(ah, bh0, acc[i][0], 0, 0, 0);
                acc[i][0] = __builtin_amdgcn_mfma_f32_16x16x32_bf16(ah, bl0, acc[i][0], 0, 0, 0);
                acc[i][0] = __builtin_amdgcn_mfma_f32_16x16x32_bf16(al, bh0, acc[i][0], 0, 0, 0);
                acc[i][1] = __builtin_amdgcn_mfma_f32_16x16x32_bf16(ah, bh1, acc[i][1], 0, 0, 0);
                acc[i][1] = __builtin_amdgcn_mfma_f32_16x16x32_bf16(ah, bl1, acc[i][1], 0, 0, 0);
                acc[i][1] = __builtin_amdgcn_mfma_f32_16x16x32_bf16(al, bh1, acc[i][1], 0, 0, 0);
            }
        }
    }

    // --- epilogue: quantize hi into LDS (swizzled), 16B coalesced stores ---
    __syncthreads();  // all waves done reading A/B tiles
    char* hB = reinterpret_cast<char*>(&Ah_s[0][0]);
    #pragma unroll
    for (int i = 0; i < 4; ++i)
        #pragma unroll
        for (int r = 0; r < 4; ++r) {
            const int row = wq + i * 16 + ((lane >> 4) << 2) + r;
            #pragma unroll
            for (int j = 0; j < 2; ++j) {
                const int col = wk + j * 16 + (lane & 15);
                const int bo = (row << 7) + (((col << 1)) ^ ((row & 7) << 4));
                *reinterpret_cast<unsigned short*>(hB + bo) = bf16_rne(acc[i][j][r]);
            }
        }
    __syncthreads();
    const int tid = threadIdx.x;
    #pragma unroll
    for (int s = 0; s < 4; ++s) {
        const int slot = s * 256 + tid;   // 0..1023 ; 8 slots (16B) per row
        const int row = slot >> 3;
        const int sl = slot & 7;
        const int bo = (row << 7) + (((sl << 4)) ^ ((row & 7) << 4));
        u32x4 hv = *reinterpret_cast<const u32x4*>(hB + bo);
        const size_t go = (size_t)(rBase + row) * DD + cBase + (sl << 3);
        *reinterpret_cast<u32x4*>(Th_g + go) = hv;
    }
}

// ---------------------------------------------------------------------------
// Fused MFMA scores + batch-softmax + masked q-reduction into wsum[b,k].
// Round 11: EXACT round-9 kernel (best measured: 151 us). launch_bounds
// (256,3) — the kernel needs ~212 unified regs (84 + 128 acc); (256,5)
// forced a 102-reg cap and spilled the accumulator (R10: WRITE_SIZE
// 30->389 MB, 151->265 us). Registers, not LDS, bound occupancy here.
// ---------------------------------------------------------------------------
__global__ __launch_bounds__(256, 3) void scores_wsum(
    const unsigned short* __restrict__ Qh_g,
    const unsigned short* __restrict__ Kh_g, const unsigned short* __restrict__ Kl_g,
    const int* __restrict__ lens, float* __restrict__ wsum) {
    __shared__ unsigned short Qh_s[128][64];
    __shared__ unsigned short Kh_s[64][64];
    __shared__ unsigned short Kl_s[64][64];

    const int qBase = blockIdx.x * 128;
    const int kBase = blockIdx.y * 64;
    const int w = threadIdx.x >> 6;
    const int lane = threadIdx.x & 63;
    const int wq = (w >> 1) * 64;   // 0 or 64
    const int wk = (w & 1) * 32;    // 0 or 32

    const int l0 = lens[0], l1 = lens[1], l2 = lens[2], l3 = lens[3];

    f32x4 acc[4][4][2] = {};  // [b][i][j] — static indexing everywhere

    #pragma unroll
    for (int b = 0; b < BB; ++b) {
        const unsigned short* qh = Qh_g + (size_t)(b * LL + qBase) * DD;
        const unsigned short* kh = Kh_g + (size_t)(b * LL + kBase) * DD;
        const unsigned short* kl = Kl_g + (size_t)(b * LL + kBase) * DD;
        for (int dcc = 0; dcc < 8; ++dcc) {
            const int dc = dcc << 6;
            __syncthreads();
            #pragma unroll
            for (int s = 0; s < 4; ++s) {
                const int r0 = w * 32 + s * 8;
                stage8(qh + (size_t)r0 * DD + dc, &Qh_s[r0][0]);
            }
            #pragma unroll
            for (int s = 0; s < 2; ++s) {
                const int r0 = w * 16 + s * 8;
                stage8(kh + (size_t)r0 * DD + dc, &Kh_s[r0][0]);
                stage8(kl + (size_t)r0 * DD + dc, &Kl_s[r0][0]);
            }
            __syncthreads();
            #pragma unroll
            for (int kk = 0; kk < 64; kk += 32) {
                bf16x8 bh0 = ldfrag(&Kh_s[0][0], wk + 0, kk);
                bf16x8 bh1 = ldfrag(&Kh_s[0][0], wk + 16, kk);
                bf16x8 bl0 = ldfrag(&Kl_s[0][0], wk + 0, kk);
                bf16x8 bl1 = ldfrag(&Kl_s[0][0], wk + 16, kk);
                #pragma unroll
                for (int i = 0; i < 4; ++i) {
                    bf16x8 ah = ldfrag(&Qh_s[0][0], wq + i * 16, kk);
                    acc[b][i][0] = __builtin_amdgcn_mfma_f32_16x16x32_bf16(ah, bh0, acc[b][i][0], 0, 0, 0);
                    acc[b][i][0] = __builtin_amdgcn_mfma_f32_16x16x32_bf16(ah, bl0, acc[b][i][0], 0, 0, 0);
                    acc[b][i][1] = __builtin_amdgcn_mfma_f32_16x16x32_bf16(ah, bh1, acc[b][i][1], 0, 0, 0);
                    acc[b][i][1] = __builtin_amdgcn_mfma_f32_16x16x32_bf16(ah, bl1, acc[b][i][1], 0, 0, 0);
                }
            }
        }
    }

    // Epilogue: softmax across b per element, mask q rows, reduce over q.
    float psum[4][2] = {};
    #pragma unroll
    for (int i = 0; i < 4; ++i) {
        #pragma unroll
        for (int r = 0; r < 4; ++r) {
            const int q = qBase + wq + i * 16 + ((lane >> 4) << 2) + r;
            #pragma unroll
            for (int j = 0; j < 2; ++j) {
                float e0 = __expf(acc[0][i][j][r]);
                float e1 = __expf(acc[1][i][j][r]);
                float e2 = __expf(acc[2][i][j][r]);
                float e3 = __expf(acc[3][i][j][r]);
                float inv = 1.0f / (e0 + e1 + e2 + e3);
                psum[0][j] += (q < l0) ? e0 * inv : 0.0f;
                psum[1][j] += (q < l1) ? e1 * inv : 0.0f;
                psum[2][j] += (q < l2) ? e2 * inv : 0.0f;
                psum[3][j] += (q < l3) ? e3 * inv : 0.0f;
            }
        }
    }
    #pragma unroll
    for (int bb = 0; bb < 4; ++bb)
        #pragma unroll
        for (int j = 0; j < 2; ++j) {
            float v = psum[bb][j];
            v += __shfl_xor(v, 16);
            v += __shfl_xor(v, 32);
            if (lane < 16)
                atomicAdd(&wsum[bb * LL + kBase + wk + j * 16 + lane], v);
        }
}

// y[b,e] = sum_k wsum[b,k] * X[b,k,e]
__global__ __launch_bounds__(256) void wsum_x(const float* __restrict__ X,
                                              const float* __restrict__ wsum,
                                              float* __restrict__ y) {
    const int b = blockIdx.y;
    const int e = blockIdx.x * 256 + threadIdx.x;
    const int kc = blockIdx.z * 64;
    const float* Xp = X + ((size_t)b * LL + kc) * DD + e;
    const float* wp = wsum + b * LL + kc;
    float a = 0.0f;
    #pragma unroll 4
    for (int k = 0; k < 64; ++k) a = fmaf(wp[k], Xp[(size_t)k * DD], a);
    atomicAdd(&y[b * DD + e], a);
}

// out[b,d] = sum_e y[b,e] * Wv[d,e]
__global__ __launch_bounds__(256) void y_out(const float* __restrict__ Wv,
                                             const float* __restrict__ y,
                                             float* __restrict__ out) {
    const int b = blockIdx.y;
    const int d = blockIdx.x * 256 + threadIdx.x;
    const float* wv = Wv + (size_t)d * DD;
    const float* yb = y + b * DD;
    float a = 0.0f;
    #pragma unroll 4
    for (int e = 0; e < DD; e += 4) {
        float4 w4 = *reinterpret_cast<const float4*>(wv + e);
        float4 y4 = *reinterpret_cast<const float4*>(yb + e);
        a += w4.x * y4.x + w4.y * y4.y + w4.z * y4.z + w4.w * y4.w;
    }
    out[b * DD + d] = a;
}

extern "C" void kernel_launch(void* const* d_in, const int* in_sizes, int n_in,
                              void* d_out, int out_size, void* d_ws, size_t ws_size,
                              hipStream_t stream) {
    const float* X  = (const float*)d_in[0];
    const float* Wq = (const float*)d_in[1];
    const float* Wk = (const float*)d_in[2];
    const float* Wv = (const float*)d_in[3];
    const int* lens = (const int*)d_in[4];
    float* out = (float*)d_out;

    char* ws = (char*)d_ws;
    unsigned short* Xh  = (unsigned short*)ws;                              // 16 MB
    unsigned short* Xl  = (unsigned short*)(ws + ((size_t)16 << 20));       // 16 MB
    unsigned short* Th  = (unsigned short*)(ws + ((size_t)32 << 20));       // 16 MB
    unsigned short* Mth = (unsigned short*)(ws + ((size_t)64 << 20));       // 512 KB
    unsigned short* Mtl = (unsigned short*)(ws + ((size_t)64 << 20) + (512u << 10));
    float* wsum = (float*)(ws + ((size_t)65 << 20));                        // 64 KB
    float* y    = (float*)(ws + ((size_t)65 << 20) + 65536);                // 8 KB

    hipMemsetAsync(wsum, 0,
                   (size_t)BB * LL * sizeof(float) + (size_t)BB * DD * sizeof(float),
                   stream);

    dim3 blk(256);
    // fused split_x (8192 blocks) + gemm_tn_M (64 blocks); scale 1/16 in Mt
    prep<<<dim3(8256), blk, 0, stream>>>(X, Xh, Xl, Wk, Wq, Mth, Mtl, 0.0625f);
    // T[i,f] = sum_e X[i,e] Mt[f,e]  (stores Th only)
    gemm_nt_T<<<dim3(1024), blk, 0, stream>>>(Xh, Xl, Mth, Mtl, Th);
    // S = Th (Xh+Xl)^T, softmax over b, masked q-reduce
    scores_wsum<<<dim3(32, 64), blk, 0, stream>>>(Th, Xh, Xl, lens, wsum);
    wsum_x<<<dim3(2, 4, 64), blk, 0, stream>>>(X, wsum, y);
    y_out<<<dim3(2, 4), blk, 0, stream>>>(Wv, y, out);
}

// Round 12
// 301.457 us; speedup vs baseline: 1.4107x; 1.0330x over previous
//
#include <hip/hip_runtime.h>

#define BB 4
#define LL 4096
#define DD 512

typedef __attribute__((ext_vector_type(8))) short bf16x8;
typedef __attribute__((ext_vector_type(4))) float f32x4;
typedef __attribute__((ext_vector_type(4))) unsigned short ushort4v;
typedef __attribute__((ext_vector_type(4))) unsigned int u32x4;

__device__ __forceinline__ unsigned short bf16_rne(float x) {
    unsigned u = __float_as_uint(x);
    unsigned r = (u + 0x7FFFu + ((u >> 16) & 1u)) >> 16;
    return (unsigned short)r;
}

// ---------------------------------------------------------------------------
// prep: fused {split_x | gemm_tn_M} — independent work, one launch.
//   blocks [0, 8192):  X fp32 -> (Xh, Xl) bf16 hi/lo pair (4 elems/thread)
//   blocks [8192, 8256): Mt[i,j] = scale * sum_d Wk[d,i] * Wq[d,j]  (64x64)
// ---------------------------------------------------------------------------
__global__ __launch_bounds__(256) void prep(
    const float* __restrict__ X,
    unsigned short* __restrict__ Xh, unsigned short* __restrict__ Xl,
    const float* __restrict__ A,  // Wk
    const float* __restrict__ B,  // Wq
    unsigned short* __restrict__ Mh, unsigned short* __restrict__ Ml,
    float scale) {
    __shared__ float As[16][68];
    __shared__ float Bs[16][68];

    if (blockIdx.x < 8192) {
        const size_t i = ((size_t)blockIdx.x * 256 + threadIdx.x) * 4;
        float4 x4 = *reinterpret_cast<const float4*>(X + i);
        float v[4] = {x4.x, x4.y, x4.z, x4.w};
        ushort4v h4, l4;
        #pragma unroll
        for (int j = 0; j < 4; ++j) {
            unsigned short h = bf16_rne(v[j]);
            float lo = v[j] - __uint_as_float((unsigned)h << 16);
            h4[j] = h;
            l4[j] = bf16_rne(lo);
        }
        *reinterpret_cast<ushort4v*>(Xh + i) = h4;
        *reinterpret_cast<ushort4v*>(Xl + i) = l4;
        return;
    }

    const int bid = blockIdx.x - 8192;
    const int tid = threadIdx.x;
    const int tx = tid & 15, ty = tid >> 4;
    const int iBase = (bid >> 3) * 64;
    const int jBase = (bid & 7) * 64;
    const int dr = tid >> 4;
    const int c4 = (tid & 15) << 2;

    float acc[4][4] = {};
    for (int d0 = 0; d0 < DD; d0 += 16) {
        float4 a4 = *reinterpret_cast<const float4*>(A + (size_t)(d0 + dr) * DD + iBase + c4);
        float4 b4 = *reinterpret_cast<const float4*>(B + (size_t)(d0 + dr) * DD + jBase + c4);
        __syncthreads();
        *reinterpret_cast<float4*>(&As[dr][c4]) = a4;
        *reinterpret_cast<float4*>(&Bs[dr][c4]) = b4;
        __syncthreads();
        #pragma unroll
        for (int t = 0; t < 16; ++t) {
            float4 q4 = *reinterpret_cast<const float4*>(&As[t][ty << 2]);
            float4 k4 = *reinterpret_cast<const float4*>(&Bs[t][tx << 2]);
            float q[4] = {q4.x, q4.y, q4.z, q4.w};
            float k[4] = {k4.x, k4.y, k4.z, k4.w};
            #pragma unroll
            for (int i = 0; i < 4; ++i)
                #pragma unroll
                for (int j = 0; j < 4; ++j)
                    acc[i][j] = fmaf(q[i], k[j], acc[i][j]);
        }
    }
    #pragma unroll
    for (int i = 0; i < 4; ++i)
        #pragma unroll
        for (int j = 0; j < 4; ++j) {
            float v = acc[i][j] * scale;
            unsigned short h = bf16_rne(v);
            float lo = v - __uint_as_float((unsigned)h << 16);
            size_t off = (size_t)(iBase + (ty << 2) + i) * DD + jBase + (tx << 2) + j;
            Mh[off] = h;
            Ml[off] = bf16_rne(lo);
        }
}

// ---------------------------------------------------------------------------
// Staging helpers (round-2/3 validated).
// ---------------------------------------------------------------------------
#define GLOAD_LDS16(SRC, DST)                                                  \
    __builtin_amdgcn_global_load_lds(                                          \
        (const __attribute__((address_space(1))) void*)(SRC),                  \
        (__attribute__((address_space(3))) void*)(DST), 16, 0, 0)

// stage 8 rows x 64 bf16 cols (1 KB), linear LDS dest, source column chunk
// pre-swizzled c^r (row0 must be a multiple of 8).
__device__ __forceinline__ void stage8(const unsigned short* __restrict__ g,
                                       unsigned short* l) {
    const int ln = threadIdx.x & 63;
    const int r = ln >> 3;
    const int c = ln & 7;
    const unsigned short* src = g + (size_t)r * DD + ((c ^ r) << 3);
    GLOAD_LDS16(src, l);
}

// read one 16x32 fragment with the read-side XOR swizzle.
__device__ __forceinline__ bf16x8 ldfrag(const unsigned short* base, int row16,
                                         int kk) {
    const int lane = threadIdx.x & 63;
    const int r = row16 + (lane & 15);
    const int boff = r * 128 + ((((kk + ((lane >> 4) << 3)) << 1)) ^ ((r & 7) << 4));
    return *reinterpret_cast<const bf16x8*>(
        reinterpret_cast<const char*>(base) + boff);
}

// ---------------------------------------------------------------------------
// T = Xsplit @ Mtsplit^T ("NT"). Round 12: 2-product input path
// (Xh·Mh + Xh·Ml). The dropped Xl·Mh term is ~2^-10 relative to T — below
// the epilogue's own bf16 rounding (2^-9), so output precision is dominated
// by the Th quantization either way. Removes Al staging (12->8 gloads/wave,
// LDS 48->32 KB) and 1/3 of MFMA. XCD swizzle + coalesced epilogue kept.
// ---------------------------------------------------------------------------
__global__ __launch_bounds__(256, 3) void gemm_nt_T(
    const unsigned short* __restrict__ Xh_g,
    const unsigned short* __restrict__ Mh_g, const unsigned short* __restrict__ Ml_g,
    unsigned short* __restrict__ Th_g) {
    __shared__ unsigned short Ah_s[128][64];
    __shared__ unsigned short Bh_s[64][64];
    __shared__ unsigned short Bl_s[64][64];

    // bijective swizzle: 1024 blocks, XCD gets 16 row-tiles x all 8 col-tiles
    const int lin = blockIdx.x;
    const int wgid = ((lin & 7) << 7) + (lin >> 3);
    const int rBase = (wgid >> 3) * 128;
    const int cBase = (wgid & 7) * 64;

    const int w = threadIdx.x >> 6;
    const int lane = threadIdx.x & 63;
    const int wq = (w >> 1) * 64;
    const int wk = (w & 1) * 32;

    f32x4 acc[4][2] = {};

    for (int dcc = 0; dcc < 8; ++dcc) {
        const int dc = dcc << 6;
        __syncthreads();
        #pragma unroll
        for (int s = 0; s < 4; ++s) {
            const int r0 = w * 32 + s * 8;
            stage8(Xh_g + (size_t)(rBase + r0) * DD + dc, &Ah_s[r0][0]);
        }
        #pragma unroll
        for (int s = 0; s < 2; ++s) {
            const int r0 = w * 16 + s * 8;
            stage8(Mh_g + (size_t)(cBase + r0) * DD + dc, &Bh_s[r0][0]);
            stage8(Ml_g + (size_t)(cBase + r0) * DD + dc, &Bl_s[r0][0]);
        }
        __syncthreads();
        #pragma unroll
        for (int kk = 0; kk < 64; kk += 32) {
            bf16x8 bh0 = ldfrag(&Bh_s[0][0], wk + 0, kk);
            bf16x8 bh1 = ldfrag(&Bh_s[0][0], wk + 16, kk);
            bf16x8 bl0 = ldfrag(&Bl_s[0][0], wk + 0, kk);
            bf16x8 bl1 = ldfrag(&Bl_s[0][0], wk + 16, kk);
            #pragma unroll
            for (int i = 0; i < 4; ++i) {
                bf16x8 ah = ldfrag(&Ah_s[0][0], wq + i * 16, kk);
                acc[i][0] = __builtin_amdgcn_mfma_f32_16x16x32_bf16(ah, bh0, acc[i][0], 0, 0, 0);
                acc[i][0] = __builtin_amdgcn_mfma_f32_16x16x32_bf16(ah, bl0, acc[i][0], 0, 0, 0);
                acc[i][1] = __builtin_amdgcn_mfma_f32_16x16x32_bf16(ah, bh1, acc[i][1], 0, 0, 0);
                acc[i][1] = __builtin_amdgcn_mfma_f32_16x16x32_bf16(ah, bl1, acc[i][1], 0, 0, 0);
            }
        }
    }

    // --- epilogue: quantize hi into LDS (swizzled), 16B coalesced stores ---
    __syncthreads();  // all waves done reading A/B tiles
    char* hB = reinterpret_cast<char*>(&Ah_s[0][0]);
    #pragma unroll
    for (int i = 0; i < 4; ++i)
        #pragma unroll
        for (int r = 0; r < 4; ++r) {
            const int row = wq + i * 16 + ((lane >> 4) << 2) + r;
            #pragma unroll
            for (int j = 0; j < 2; ++j) {
                const int col = wk + j * 16 + (lane & 15);
                const int bo = (row << 7) + (((col << 1)) ^ ((row & 7) << 4));
                *reinterpret_cast<unsigned short*>(hB + bo) = bf16_rne(acc[i][j][r]);
            }
        }
    __syncthreads();
    const int tid = threadIdx.x;
    #pragma unroll
    for (int s = 0; s < 4; ++s) {
        const int slot = s * 256 + tid;   // 0..1023 ; 8 slots (16B) per row
        const int row = slot >> 3;
        const int sl = slot & 7;
        const int bo = (row << 7) + (((sl << 4)) ^ ((row & 7) << 4));
        u32x4 hv = *reinterpret_cast<const u32x4*>(hB + bo);
        const size_t go = (size_t)(rBase + row) * DD + cBase + (sl << 3);
        *reinterpret_cast<u32x4*>(Th_g + go) = hv;
    }
}

// ---------------------------------------------------------------------------
// Fused MFMA scores + batch-softmax + masked q-reduction into wsum[b,k].
// EXACT round-9/11 kernel (best measured: 150 us, 916 TF effective).
// (256,3): kernel needs ~212 unified regs (84 + 128 acc); higher occupancy
// spills (R10). Registers, not LDS, bound occupancy here.
// ---------------------------------------------------------------------------
__global__ __launch_bounds__(256, 3) void scores_wsum(
    const unsigned short* __restrict__ Qh_g,
    const unsigned short* __restrict__ Kh_g, const unsigned short* __restrict__ Kl_g,
    const int* __restrict__ lens, float* __restrict__ wsum) {
    __shared__ unsigned short Qh_s[128][64];
    __shared__ unsigned short Kh_s[64][64];
    __shared__ unsigned short Kl_s[64][64];

    const int qBase = blockIdx.x * 128;
    const int kBase = blockIdx.y * 64;
    const int w = threadIdx.x >> 6;
    const int lane = threadIdx.x & 63;
    const int wq = (w >> 1) * 64;   // 0 or 64
    const int wk = (w & 1) * 32;    // 0 or 32

    const int l0 = lens[0], l1 = lens[1], l2 = lens[2], l3 = lens[3];

    f32x4 acc[4][4][2] = {};  // [b][i][j] — static indexing everywhere

    #pragma unroll
    for (int b = 0; b < BB; ++b) {
        const unsigned short* qh = Qh_g + (size_t)(b * LL + qBase) * DD;
        const unsigned short* kh = Kh_g + (size_t)(b * LL + kBase) * DD;
        const unsigned short* kl = Kl_g + (size_t)(b * LL + kBase) * DD;
        for (int dcc = 0; dcc < 8; ++dcc) {
            const int dc = dcc << 6;
            __syncthreads();
            #pragma unroll
            for (int s = 0; s < 4; ++s) {
                const int r0 = w * 32 + s * 8;
                stage8(qh + (size_t)r0 * DD + dc, &Qh_s[r0][0]);
            }
            #pragma unroll
            for (int s = 0; s < 2; ++s) {
                const int r0 = w * 16 + s * 8;
                stage8(kh + (size_t)r0 * DD + dc, &Kh_s[r0][0]);
                stage8(kl + (size_t)r0 * DD + dc, &Kl_s[r0][0]);
            }
            __syncthreads();
            #pragma unroll
            for (int kk = 0; kk < 64; kk += 32) {
                bf16x8 bh0 = ldfrag(&Kh_s[0][0], wk + 0, kk);
                bf16x8 bh1 = ldfrag(&Kh_s[0][0], wk + 16, kk);
                bf16x8 bl0 = ldfrag(&Kl_s[0][0], wk + 0, kk);
                bf16x8 bl1 = ldfrag(&Kl_s[0][0], wk + 16, kk);
                #pragma unroll
                for (int i = 0; i < 4; ++i) {
                    bf16x8 ah = ldfrag(&Qh_s[0][0], wq + i * 16, kk);
                    acc[b][i][0] = __builtin_amdgcn_mfma_f32_16x16x32_bf16(ah, bh0, acc[b][i][0], 0, 0, 0);
                    acc[b][i][0] = __builtin_amdgcn_mfma_f32_16x16x32_bf16(ah, bl0, acc[b][i][0], 0, 0, 0);
                    acc[b][i][1] = __builtin_amdgcn_mfma_f32_16x16x32_bf16(ah, bh1, acc[b][i][1], 0, 0, 0);
                    acc[b][i][1] = __builtin_amdgcn_mfma_f32_16x16x32_bf16(ah, bl1, acc[b][i][1], 0, 0, 0);
                }
            }
        }
    }

    // Epilogue: softmax across b per element, mask q rows, reduce over q.
    float psum[4][2] = {};
    #pragma unroll
    for (int i = 0; i < 4; ++i) {
        #pragma unroll
        for (int r = 0; r < 4; ++r) {
            const int q = qBase + wq + i * 16 + ((lane >> 4) << 2) + r;
            #pragma unroll
            for (int j = 0; j < 2; ++j) {
                float e0 = __expf(acc[0][i][j][r]);
                float e1 = __expf(acc[1][i][j][r]);
                float e2 = __expf(acc[2][i][j][r]);
                float e3 = __expf(acc[3][i][j][r]);
                float inv = 1.0f / (e0 + e1 + e2 + e3);
                psum[0][j] += (q < l0) ? e0 * inv : 0.0f;
                psum[1][j] += (q < l1) ? e1 * inv : 0.0f;
                psum[2][j] += (q < l2) ? e2 * inv : 0.0f;
                psum[3][j] += (q < l3) ? e3 * inv : 0.0f;
            }
        }
    }
    #pragma unroll
    for (int bb = 0; bb < 4; ++bb)
        #pragma unroll
        for (int j = 0; j < 2; ++j) {
            float v = psum[bb][j];
            v += __shfl_xor(v, 16);
            v += __shfl_xor(v, 32);
            if (lane < 16)
                atomicAdd(&wsum[bb * LL + kBase + wk + j * 16 + lane], v);
        }
}

// y[b,e] = sum_k wsum[b,k] * X[b,k,e]
__global__ __launch_bounds__(256) void wsum_x(const float* __restrict__ X,
                                              const float* __restrict__ wsum,
                                              float* __restrict__ y) {
    const int b = blockIdx.y;
    const int e = blockIdx.x * 256 + threadIdx.x;
    const int kc = blockIdx.z * 64;
    const float* Xp = X + ((size_t)b * LL + kc) * DD + e;
    const float* wp = wsum + b * LL + kc;
    float a = 0.0f;
    #pragma unroll 4
    for (int k = 0; k < 64; ++k) a = fmaf(wp[k], Xp[(size_t)k * DD], a);
    atomicAdd(&y[b * DD + e], a);
}

// out[b,d] = sum_e y[b,e] * Wv[d,e]
__global__ __launch_bounds__(256) void y_out(const float* __restrict__ Wv,
                                             const float* __restrict__ y,
                                             float* __restrict__ out) {
    const int b = blockIdx.y;
    const int d = blockIdx.x * 256 + threadIdx.x;
    const float* wv = Wv + (size_t)d * DD;
    const float* yb = y + b * DD;
    float a = 0.0f;
    #pragma unroll 4
    for (int e = 0; e < DD; e += 4) {
        float4 w4 = *reinterpret_cast<const float4*>(wv + e);
        float4 y4 = *reinterpret_cast<const float4*>(yb + e);
        a += w4.x * y4.x + w4.y * y4.y + w4.z * y4.z + w4.w * y4.w;
    }
    out[b * DD + d] = a;
}

extern "C" void kernel_launch(void* const* d_in, const int* in_sizes, int n_in,
                              void* d_out, int out_size, void* d_ws, size_t ws_size,
                              hipStream_t stream) {
    const float* X  = (const float*)d_in[0];
    const float* Wq = (const float*)d_in[1];
    const float* Wk = (const float*)d_in[2];
    const float* Wv = (const float*)d_in[3];
    const int* lens = (const int*)d_in[4];
    float* out = (float*)d_out;

    char* ws = (char*)d_ws;
    unsigned short* Xh  = (unsigned short*)ws;                              // 16 MB
    unsigned short* Xl  = (unsigned short*)(ws + ((size_t)16 << 20));       // 16 MB
    unsigned short* Th  = (unsigned short*)(ws + ((size_t)32 << 20));       // 16 MB
    unsigned short* Mth = (unsigned short*)(ws + ((size_t)64 << 20));       // 512 KB
    unsigned short* Mtl = (unsigned short*)(ws + ((size_t)64 << 20) + (512u << 10));
    float* wsum = (float*)(ws + ((size_t)65 << 20));                        // 64 KB
    float* y    = (float*)(ws + ((size_t)65 << 20) + 65536);                // 8 KB

    hipMemsetAsync(wsum, 0,
                   (size_t)BB * LL * sizeof(float) + (size_t)BB * DD * sizeof(float),
                   stream);

    dim3 blk(256);
    // fused split_x (8192 blocks) + gemm_tn_M (64 blocks); scale 1/16 in Mt
    prep<<<dim3(8256), blk, 0, stream>>>(X, Xh, Xl, Wk, Wq, Mth, Mtl, 0.0625f);
    // T[i,f] = sum_e Xh[i,e] (Mth+Mtl)[f,e]  (stores Th only)
    gemm_nt_T<<<dim3(1024), blk, 0, stream>>>(Xh, Mth, Mtl, Th);
    // S = Th (Xh+Xl)^T, softmax over b, masked q-reduce
    scores_wsum<<<dim3(32, 64), blk, 0, stream>>>(Th, Xh, Xl, lens, wsum);
    wsum_x<<<dim3(2, 4, 64), blk, 0, stream>>>(X, wsum, y);
    y_out<<<dim3(2, 4), blk, 0, stream>>>(Wv, y, out);
}